// Round 1
// baseline (841.117 us; speedup 1.0000x reference)
//
#include <hip/hip_runtime.h>
#include <math.h>

#define EPS_F 1e-7f

constexpr int Bn   = 128;
constexpr int Sn   = 1024;
constexpr int Dn   = 256;
constexpr int ATTn = 128;
constexpr int QDn  = 128;
constexpr int Mn   = Bn * Sn;   // 131072 rows

// ---------------- ws layout (floats) ----------------
// [0, 128)                : u = W_u @ query
// [128, 128+32768)        : Wt  (W transposed, 128 x 256)
// [32896, 32896+131072)   : e   (masked exp scores, per row)

// K1: u[a] = sum_q W_u[a][q] * query[q]
__global__ void k_u(const float* __restrict__ Wu, const float* __restrict__ q,
                    float* __restrict__ u) {
    __shared__ float qs[QDn];
    int t = threadIdx.x;            // 0..127
    qs[t] = q[t];
    __syncthreads();
    float acc = 0.f;
    #pragma unroll 8
    for (int j = 0; j < QDn; ++j) acc += Wu[t * QDn + j] * qs[j];
    u[t] = acc;
}

// K1b: Wt[c][k] = W[k][c]   (W: 256x128 -> Wt: 128x256)
__global__ void k_transpose(const float* __restrict__ W, float* __restrict__ Wt) {
    __shared__ float tile[32][33];
    int k0 = blockIdx.x * 32;       // along D (256)
    int c0 = blockIdx.y * 32;       // along ATT (128)
    int lx = threadIdx.x, ly = threadIdx.y;   // 32 x 8
    #pragma unroll
    for (int i = 0; i < 32; i += 8)
        tile[ly + i][lx] = W[(size_t)(k0 + ly + i) * ATTn + c0 + lx];
    __syncthreads();
    #pragma unroll
    for (int i = 0; i < 32; i += 8)
        Wt[(size_t)(c0 + ly + i) * Dn + k0 + lx] = tile[lx][ly + i];
}

// K2: fused score GEMM.
// e[row] = exp( sum_a tanh( (key[row,:] @ W)[a] + bias[a] ) * u[a] ) * mask[row]
// BM=128 rows/block, BK=32, N=128 (full), 256 threads, 8x8 micro-tile.
__global__ __launch_bounds__(256) void k_scores(
    const float* __restrict__ key,   // (Mn, 256) row-major
    const float* __restrict__ Wt,    // (128, 256) = W^T
    const float* __restrict__ bias,  // (128)
    const float* __restrict__ u,     // (128)
    const int*   __restrict__ mask,  // (Mn)
    float* __restrict__ e)           // (Mn)
{
    // LDS tiles stored as float4 chunks, XOR-swizzled to avoid bank conflicts
    // on the row-strided fragment reads (rows differing by 8 would otherwise
    // collide at stride 32 floats).
    __shared__ float4 As4[128][8];   // logical As[row][k]; chunk c stored at c ^ ((row>>3)&7)
    __shared__ float4 Bs4[128][8];   // logical Bs[col][k]; chunk c stored at c ^ (col&7)

    const int t  = threadIdx.x;
    const int tx = t & 15;           // column group: cols tx + 16*j
    const int ty = t >> 4;           // row group: rows ty*8 + r
    const int row0 = blockIdx.x * 128;

    float acc[8][8];
    #pragma unroll
    for (int r = 0; r < 8; ++r)
        #pragma unroll
        for (int j = 0; j < 8; ++j) acc[r][j] = 0.f;

    for (int k0 = 0; k0 < Dn; k0 += 32) {
        // Load A tile: 128 rows x 32 k = 1024 float4; 4 per thread. Coalesced:
        // 8 consecutive lanes read one row's 128B segment.
        #pragma unroll
        for (int i = 0; i < 4; ++i) {
            int f  = t + i * 256;
            int r  = f >> 3;          // 0..127
            int c4 = f & 7;
            float4 v = *(const float4*)(key + (size_t)(row0 + r) * Dn + k0 + c4 * 4);
            As4[r][c4 ^ ((r >> 3) & 7)] = v;
        }
        // Load B tile from Wt (col-major-in-k): 128 cols x 32 k
        #pragma unroll
        for (int i = 0; i < 4; ++i) {
            int f  = t + i * 256;
            int c  = f >> 3;          // 0..127
            int c4 = f & 7;
            float4 v = *(const float4*)(Wt + (size_t)c * Dn + k0 + c4 * 4);
            Bs4[c][c4 ^ (c & 7)] = v;
        }
        __syncthreads();

        #pragma unroll
        for (int kc = 0; kc < 8; ++kc) {   // 4 k's per chunk
            float4 a4[8], b4[8];
            #pragma unroll
            for (int r = 0; r < 8; ++r) {
                int row = ty * 8 + r;
                a4[r] = As4[row][kc ^ ((row >> 3) & 7)];
            }
            #pragma unroll
            for (int j = 0; j < 8; ++j) {
                int col = tx + 16 * j;
                b4[j] = Bs4[col][kc ^ (col & 7)];
            }
            #pragma unroll
            for (int r = 0; r < 8; ++r)
                #pragma unroll
                for (int j = 0; j < 8; ++j)
                    acc[r][j] += a4[r].x * b4[j].x + a4[r].y * b4[j].y +
                                 a4[r].z * b4[j].z + a4[r].w * b4[j].w;
        }
        __syncthreads();
    }

    // Epilogue: per-row  sum_j tanh(acc + bias[col]) * u[col], reduce over tx.
    float bv[8], uv[8];
    #pragma unroll
    for (int j = 0; j < 8; ++j) {
        int col = tx + 16 * j;
        bv[j] = bias[col];
        uv[j] = u[col];
    }
    #pragma unroll
    for (int r = 0; r < 8; ++r) {
        float s = 0.f;
        #pragma unroll
        for (int j = 0; j < 8; ++j)
            s += tanhf(acc[r][j] + bv[j]) * uv[j];
        // butterfly over the 16-lane column group (bits 0..3 of lane id)
        s += __shfl_xor(s, 1);
        s += __shfl_xor(s, 2);
        s += __shfl_xor(s, 4);
        s += __shfl_xor(s, 8);
        if (tx == 0) {
            int row = row0 + ty * 8 + r;
            e[row] = expf(s) * (float)mask[row];
        }
    }
}

// K3: per-batch denominator + weighted sum.
// out[b][d] = (sum_s e[b,s]*key[b,s,d]) / (sum_s e[b,s] + EPS)
__global__ __launch_bounds__(1024) void k_out(
    const float* __restrict__ key, const float* __restrict__ e,
    float* __restrict__ out)
{
    __shared__ float  es[Sn];          // scores for this batch
    __shared__ float4 part[16][64];    // per-s-chunk partial sums over d
    __shared__ float  red[16];
    __shared__ float  inv_den;
    const int b = blockIdx.x;
    const int t = threadIdx.x;         // 0..1023

    // phase 1: stage scores + denominator
    float ev = e[(size_t)b * Sn + t];
    es[t] = ev;
    float s = ev;
    #pragma unroll
    for (int m = 1; m < 64; m <<= 1) s += __shfl_xor(s, m);
    if ((t & 63) == 0) red[t >> 6] = s;
    __syncthreads();
    if (t == 0) {
        float tot = 0.f;
        #pragma unroll
        for (int w = 0; w < 16; ++w) tot += red[w];
        inv_den = 1.0f / (tot + EPS_F);
    }

    // phase 2: weighted sum. thread -> (s-chunk sc, float4 d-lane dq)
    const int dq = t & 63;
    const int sc = t >> 6;
    const float4* key4 = (const float4*)(key + (size_t)b * Sn * Dn);
    float4 acc = make_float4(0.f, 0.f, 0.f, 0.f);
    #pragma unroll 4
    for (int s2 = sc * 64; s2 < sc * 64 + 64; ++s2) {
        float w   = es[s2];
        float4 kv = key4[s2 * 64 + dq];
        acc.x += w * kv.x; acc.y += w * kv.y;
        acc.z += w * kv.z; acc.w += w * kv.w;
    }
    part[sc][dq] = acc;
    __syncthreads();

    if (t < 64) {
        float4 o = make_float4(0.f, 0.f, 0.f, 0.f);
        #pragma unroll
        for (int c = 0; c < 16; ++c) {
            float4 p = part[c][t];
            o.x += p.x; o.y += p.y; o.z += p.z; o.w += p.w;
        }
        float id = inv_den;
        o.x *= id; o.y *= id; o.z *= id; o.w *= id;
        *(float4*)(out + (size_t)b * Dn + t * 4) = o;
    }
}

extern "C" void kernel_launch(void* const* d_in, const int* in_sizes, int n_in,
                              void* d_out, int out_size, void* d_ws, size_t ws_size,
                              hipStream_t stream) {
    const float* key   = (const float*)d_in[0];
    const float* query = (const float*)d_in[1];
    const int*   mask  = (const int*)d_in[2];
    const float* W     = (const float*)d_in[3];
    const float* bias  = (const float*)d_in[4];
    const float* Wu    = (const float*)d_in[5];
    float* out = (float*)d_out;

    float* ws = (float*)d_ws;
    float* u  = ws;
    float* Wt = ws + 128;
    float* e  = ws + 128 + 32768;

    hipLaunchKernelGGL(k_u,         dim3(1),        dim3(128),       0, stream, Wu, query, u);
    hipLaunchKernelGGL(k_transpose, dim3(8, 4),     dim3(32, 8),     0, stream, W, Wt);
    hipLaunchKernelGGL(k_scores,    dim3(Mn / 128), dim3(256),       0, stream, key, Wt, bias, u, mask, e);
    hipLaunchKernelGGL(k_out,       dim3(Bn),       dim3(1024),      0, stream, key, e, out);
}

// Round 2
// 99.853 us; speedup vs baseline: 8.4236x; 8.4236x over previous
//
#include <hip/hip_runtime.h>
#include <hip/hip_bf16.h>
#include <math.h>

#define EPS_F 1e-7f

constexpr int Bn = 128, Sn = 1024, Dn = 256, ATTn = 128, QDn = 128;
constexpr int Mn = Bn * Sn;          // 131072 rows
constexpr int BM = 128;              // rows per block
constexpr int NBLK = Mn / BM;        // 1024 blocks
constexpr int KSTEPS = Dn / 32;      // 8 MFMA k-steps
constexpr int NJ = ATTn / 16;        // 8 column fragments

typedef short short8 __attribute__((ext_vector_type(8)));
typedef float f32x4  __attribute__((ext_vector_type(4)));

__device__ inline ushort f2bf(float f) {
    __hip_bfloat16 h = __float2bfloat16(f);   // RNE
    ushort u; __builtin_memcpy(&u, &h, 2); return u;
}
__device__ inline float bf2f(ushort u) {
    __hip_bfloat16 h; __builtin_memcpy(&h, &u, 2); return __bfloat162float(h);
}

// ---------------- ws layout (bytes) ----------------
// [0,512)            u (128 f32)
// [512,66048)        Bhi  (8 ks * 8 j * 64 lane * 8 bf16)
// [66048,131584)     Blo
// [131584,1180160)   P    (1024 blk * 256 d f32)
// [1180160,1184256)  den  (1024 f32)

// K1: u = W_u @ query
__global__ void k_u(const float* __restrict__ Wu, const float* __restrict__ q,
                    float* __restrict__ u) {
    __shared__ float qs[QDn];
    int t = threadIdx.x;
    qs[t] = q[t];
    __syncthreads();
    float acc = 0.f;
    #pragma unroll 8
    for (int j = 0; j < QDn; ++j) acc += Wu[t * QDn + j] * qs[j];
    u[t] = acc;
}

// K1b: W (256x128 fp32) -> MFMA-fragment-ordered bf16 hi/lo.
// Fragment (ks,j): lane l holds col = 16j+(l&15), k = 32ks+(l>>4)*8+i, i=0..7.
__global__ __launch_bounds__(256) void k_bprep(const float* __restrict__ W,
        ushort* __restrict__ Bhi, ushort* __restrict__ Blo) {
    int gid  = blockIdx.x * 256 + threadIdx.x;   // 0..4095
    int lane = gid & 63;
    int j    = (gid >> 6) & 7;
    int ks   = gid >> 9;
    int col  = j * 16 + (lane & 15);
    int kb   = ks * 32 + (lane >> 4) * 8;
    #pragma unroll
    for (int i = 0; i < 8; ++i) {
        float f  = W[(size_t)(kb + i) * ATTn + col];
        ushort h = f2bf(f);
        ushort l = f2bf(f - bf2f(h));
        size_t idx = (size_t)gid * 8 + i;
        Bhi[idx] = h; Blo[idx] = l;
    }
}

// K2: fused scores + partial weighted sums.
// Per block: rows row0..row0+127, full N=128, K=256 via bf16-split MFMA.
// Then phase 2: P[d] = sum_rows e*key (tile is L2-hot), partial denominator.
__global__ __launch_bounds__(256) void k_scores(
    const float*  __restrict__ key,
    const ushort* __restrict__ Bhi, const ushort* __restrict__ Blo,
    const float*  __restrict__ bias, const float* __restrict__ u,
    const int*    __restrict__ mask,
    float* __restrict__ P, float* __restrict__ den)
{
    __shared__ float es[BM];
    const int t    = threadIdx.x;
    const int lane = t & 63;
    const int w    = t >> 6;        // wave 0..3 -> rows w*32..w*32+31
    const int gb   = blockIdx.x;
    const int row0 = gb * BM;
    const int l15  = lane & 15;
    const int lg   = lane >> 4;     // 0..3

    f32x4 acc[2][NJ];
    #pragma unroll
    for (int rf = 0; rf < 2; ++rf)
        #pragma unroll
        for (int j = 0; j < NJ; ++j)
            acc[rf][j] = (f32x4){0.f, 0.f, 0.f, 0.f};

    const int arow0 = row0 + w * 32 + l15;       // fragment rf adds rf*16

    for (int ks = 0; ks < KSTEPS; ++ks) {
        short8 ahi[2], alo[2];
        #pragma unroll
        for (int rf = 0; rf < 2; ++rf) {
            const float* src = key + (size_t)(arow0 + rf * 16) * Dn + ks * 32 + lg * 8;
            float4 v0 = *(const float4*)(src);
            float4 v1 = *(const float4*)(src + 4);
            float f[8] = {v0.x, v0.y, v0.z, v0.w, v1.x, v1.y, v1.z, v1.w};
            #pragma unroll
            for (int i = 0; i < 8; ++i) {
                ushort h = f2bf(f[i]);
                ahi[rf][i] = (short)h;
                alo[rf][i] = (short)f2bf(f[i] - bf2f(h));
            }
        }
        #pragma unroll
        for (int j = 0; j < NJ; ++j) {
            const size_t boff = ((size_t)(ks * NJ + j) * 64 + lane) * 8;
            short8 bh = *(const short8*)(Bhi + boff);
            short8 bl = *(const short8*)(Blo + boff);
            #pragma unroll
            for (int rf = 0; rf < 2; ++rf) {
                acc[rf][j] = __builtin_amdgcn_mfma_f32_16x16x32_bf16(ahi[rf], bh, acc[rf][j], 0, 0, 0);
                acc[rf][j] = __builtin_amdgcn_mfma_f32_16x16x32_bf16(ahi[rf], bl, acc[rf][j], 0, 0, 0);
                acc[rf][j] = __builtin_amdgcn_mfma_f32_16x16x32_bf16(alo[rf], bh, acc[rf][j], 0, 0, 0);
            }
        }
    }

    // Epilogue: s(row) = sum_col tanh(acc + bias[col]) * u[col]; e = exp(s)*mask.
    // C/D layout (HW-verified): col = 16j + (lane&15), row = base + (lane>>4)*4 + reg.
    float uv[NJ], bv[NJ];
    #pragma unroll
    for (int j = 0; j < NJ; ++j) {
        int col = j * 16 + l15;
        uv[j] = u[col]; bv[j] = bias[col];
    }
    #pragma unroll
    for (int rf = 0; rf < 2; ++rf) {
        #pragma unroll
        for (int reg = 0; reg < 4; ++reg) {
            float s = 0.f;
            #pragma unroll
            for (int j = 0; j < NJ; ++j)
                s += tanhf(acc[rf][j][reg] + bv[j]) * uv[j];
            s += __shfl_xor(s, 1);
            s += __shfl_xor(s, 2);
            s += __shfl_xor(s, 4);
            s += __shfl_xor(s, 8);
            if (l15 == 0) {
                int rl = w * 32 + rf * 16 + lg * 4 + reg;
                es[rl] = expf(s) * (float)mask[row0 + rl];
            }
        }
    }
    __syncthreads();

    // denominator partial for this block
    if (t < 64) {
        float v = es[t] + es[t + 64];
        #pragma unroll
        for (int m = 1; m < 64; m <<= 1) v += __shfl_xor(v, m);
        if (t == 0) den[gb] = v;
    }

    // phase 2: P[d] = sum_s es[s] * key[row0+s][d]; thread t owns d = t.
    float p = 0.f;
    #pragma unroll 8
    for (int s = 0; s < BM; ++s)
        p += es[s] * key[(size_t)(row0 + s) * Dn + t];
    P[(size_t)gb * Dn + t] = p;
}

// K3: combine 8 block-partials per batch, normalize.
__global__ __launch_bounds__(256) void k_final(const float* __restrict__ P,
        const float* __restrict__ den, float* __restrict__ out) {
    int b = blockIdx.x, t = threadIdx.x;
    float dtot = 0.f;
    #pragma unroll
    for (int k = 0; k < 8; ++k) dtot += den[b * 8 + k];
    float o = 0.f;
    #pragma unroll
    for (int k = 0; k < 8; ++k) o += P[(size_t)(b * 8 + k) * Dn + t];
    out[(size_t)b * Dn + t] = o / (dtot + EPS_F);
}

extern "C" void kernel_launch(void* const* d_in, const int* in_sizes, int n_in,
                              void* d_out, int out_size, void* d_ws, size_t ws_size,
                              hipStream_t stream) {
    const float* key   = (const float*)d_in[0];
    const float* query = (const float*)d_in[1];
    const int*   mask  = (const int*)d_in[2];
    const float* W     = (const float*)d_in[3];
    const float* bias  = (const float*)d_in[4];
    const float* Wu    = (const float*)d_in[5];
    float* out = (float*)d_out;

    char* ws = (char*)d_ws;
    float*  u   = (float*)(ws);
    ushort* Bhi = (ushort*)(ws + 512);
    ushort* Blo = (ushort*)(ws + 66048);
    float*  P   = (float*)(ws + 131584);
    float*  den = (float*)(ws + 1180160);

    hipLaunchKernelGGL(k_u,      dim3(1),    dim3(128), 0, stream, Wu, query, u);
    hipLaunchKernelGGL(k_bprep,  dim3(16),   dim3(256), 0, stream, W, Bhi, Blo);
    hipLaunchKernelGGL(k_scores, dim3(NBLK), dim3(256), 0, stream,
                       key, Bhi, Blo, bias, u, mask, P, den);
    hipLaunchKernelGGL(k_final,  dim3(Bn),   dim3(256), 0, stream, P, den, out);
}

// Round 3
// 92.511 us; speedup vs baseline: 9.0921x; 1.0794x over previous
//
#include <hip/hip_runtime.h>
#include <hip/hip_bf16.h>
#include <math.h>

#define EPS_F 1e-7f

constexpr int Bn = 128, Sn = 1024, Dn = 256, ATTn = 128, QDn = 128;
constexpr int Mn = Bn * Sn;          // 131072 rows
constexpr int BM = 64;               // rows per block
constexpr int NBLK = Mn / BM;        // 2048 blocks
constexpr int KSTEPS = Dn / 32;      // 8 MFMA k-steps
constexpr int NJ = ATTn / 16;        // 8 column fragments

typedef short short8 __attribute__((ext_vector_type(8)));
typedef float f32x4  __attribute__((ext_vector_type(4)));

// Exact truncation split: f = hi + r exactly (hi = top-16-bit float),
// lo = bf16_rne(r). hi*B + lo*B represents f*B to ~2^-17 relative.
__device__ inline void split_bf(float f, ushort& hi, ushort& lo) {
    uint fb = __float_as_uint(f);
    hi = (ushort)(fb >> 16);
    float hf = __uint_as_float(fb & 0xffff0000u);
    float lf = f - hf;                       // exact
    __hip_bfloat16 lb = __float2bfloat16(lf);
    __builtin_memcpy(&lo, &lb, 2);
}

__device__ inline float tanh_fast(float x) {
    float cx = fminf(9.0f, fmaxf(-9.0f, x));
    float e = __builtin_amdgcn_exp2f(cx * 2.8853900817779268f);  // e^{2x}
    return (e - 1.0f) * __builtin_amdgcn_rcpf(e + 1.0f);
}

// ---------------- ws layout (bytes) ----------------
// [0,512)              u (128 f32)
// [512,66048)          Bhi (8ks * 8j * 64lane * 8 bf16)
// [66048,131584)       Blo
// [131584,2228736)     P   (2048 blk * 256 d f32)
// [2228736,2236928)    den (2048 f32)

__global__ void k_u(const float* __restrict__ Wu, const float* __restrict__ q,
                    float* __restrict__ u) {
    __shared__ float qs[QDn];
    int t = threadIdx.x;
    qs[t] = q[t];
    __syncthreads();
    float acc = 0.f;
    #pragma unroll 8
    for (int j = 0; j < QDn; ++j) acc += Wu[t * QDn + j] * qs[j];
    u[t] = acc;
}

// W (256x128 fp32) -> MFMA-B-fragment-ordered bf16 hi/lo.
// Fragment (ks,j): lane l holds col = 16j+(l&15), k = 32ks+(l>>4)*8+i.
__global__ __launch_bounds__(256) void k_bprep(const float* __restrict__ W,
        ushort* __restrict__ Bhi, ushort* __restrict__ Blo) {
    int gid  = blockIdx.x * 256 + threadIdx.x;   // 0..4095
    int lane = gid & 63;
    int j    = (gid >> 6) & 7;
    int ks   = gid >> 9;
    int col  = j * 16 + (lane & 15);
    int kb   = ks * 32 + (lane >> 4) * 8;
    #pragma unroll
    for (int i = 0; i < 8; ++i) {
        float f = W[(size_t)(kb + i) * ATTn + col];
        ushort h, l;
        split_bf(f, h, l);
        size_t idx = (size_t)gid * 8 + i;
        Bhi[idx] = h; Blo[idx] = l;
    }
}

// Fused: scores (bf16-split MFMA, K=256, N=128) + partial weighted sums.
__global__ __launch_bounds__(256, 6) void k_scores(
    const float*  __restrict__ key,
    const ushort* __restrict__ Bhi, const ushort* __restrict__ Blo,
    const float*  __restrict__ bias, const float* __restrict__ u,
    const int*    __restrict__ mask,
    float* __restrict__ P, float* __restrict__ den)
{
    __shared__ float  es[BM];
    __shared__ float4 part[4][64];
    const int t    = threadIdx.x;
    const int lane = t & 63;
    const int w    = t >> 6;        // wave 0..3 -> rows w*16..w*16+15
    const int gb   = blockIdx.x;
    const int row0 = gb * BM;
    const int l15  = lane & 15;
    const int lg   = lane >> 4;

    f32x4 acc[NJ];
    #pragma unroll
    for (int j = 0; j < NJ; ++j) acc[j] = (f32x4){0.f, 0.f, 0.f, 0.f};

    const float* abase = key + (size_t)(row0 + w * 16 + l15) * Dn + lg * 8;

    for (int ks = 0; ks < KSTEPS; ++ks) {
        float4 v0 = *(const float4*)(abase + ks * 32);
        float4 v1 = *(const float4*)(abase + ks * 32 + 4);
        float f[8] = {v0.x, v0.y, v0.z, v0.w, v1.x, v1.y, v1.z, v1.w};
        short8 ah, al;
        #pragma unroll
        for (int i = 0; i < 8; ++i) {
            ushort h, l;
            split_bf(f[i], h, l);
            ah[i] = (short)h; al[i] = (short)l;
        }
        #pragma unroll
        for (int j = 0; j < NJ; ++j) {
            const size_t boff = ((size_t)(ks * NJ + j) * 64 + lane) * 8;
            short8 bh = *(const short8*)(Bhi + boff);
            short8 bl = *(const short8*)(Blo + boff);
            acc[j] = __builtin_amdgcn_mfma_f32_16x16x32_bf16(ah, bh, acc[j], 0, 0, 0);
            acc[j] = __builtin_amdgcn_mfma_f32_16x16x32_bf16(ah, bl, acc[j], 0, 0, 0);
            acc[j] = __builtin_amdgcn_mfma_f32_16x16x32_bf16(al, bh, acc[j], 0, 0, 0);
        }
    }

    // Epilogue: s(row) = sum_col tanh(acc+bias)*u; e = exp(s)*mask.
    // C/D layout: col = 16j + l15, row(frag-local) = lg*4 + reg.
    float s4[4] = {0.f, 0.f, 0.f, 0.f};
    #pragma unroll
    for (int j = 0; j < NJ; ++j) {
        int col = j * 16 + l15;
        float bv = bias[col], uvv = u[col];
        #pragma unroll
        for (int reg = 0; reg < 4; ++reg)
            s4[reg] += tanh_fast(acc[j][reg] + bv) * uvv;
    }
    #pragma unroll
    for (int reg = 0; reg < 4; ++reg) {
        float s = s4[reg];
        s += __shfl_xor(s, 1);
        s += __shfl_xor(s, 2);
        s += __shfl_xor(s, 4);
        s += __shfl_xor(s, 8);
        if (l15 == 0) {
            int rl = w * 16 + lg * 4 + reg;
            es[rl] = __builtin_amdgcn_exp2f(s * 1.4426950408889634f)
                     * (float)mask[row0 + rl];
        }
    }
    __syncthreads();

    // block-partial denominator
    if (t < 64) {
        float v = es[t];
        #pragma unroll
        for (int m = 1; m < 64; m <<= 1) v += __shfl_xor(v, m);
        if (t == 0) den[gb] = v;
    }

    // phase 2: P[d] = sum_s es[s]*key[row0+s][d]  (tile is L2-hot)
    const int dq = t & 63;          // float4 lane over d
    const int sc = t >> 6;          // s-chunk (16 rows each)
    const float4* key4 = (const float4*)(key + (size_t)row0 * Dn);
    float4 a2 = make_float4(0.f, 0.f, 0.f, 0.f);
    #pragma unroll 4
    for (int s2 = sc * 16; s2 < sc * 16 + 16; ++s2) {
        float wv  = es[s2];
        float4 kv = key4[(size_t)s2 * 64 + dq];
        a2.x += wv * kv.x; a2.y += wv * kv.y;
        a2.z += wv * kv.z; a2.w += wv * kv.w;
    }
    part[sc][dq] = a2;
    __syncthreads();
    if (t < 64) {
        float4 o = part[0][t];
        #pragma unroll
        for (int c = 1; c < 4; ++c) {
            float4 p = part[c][t];
            o.x += p.x; o.y += p.y; o.z += p.z; o.w += p.w;
        }
        *(float4*)(P + (size_t)gb * Dn + t * 4) = o;
    }
}

// combine 16 block-partials per batch, normalize.
__global__ __launch_bounds__(256) void k_final(const float* __restrict__ P,
        const float* __restrict__ den, float* __restrict__ out) {
    int b = blockIdx.x, t = threadIdx.x;
    float dtot = 0.f;
    #pragma unroll
    for (int k = 0; k < 16; ++k) dtot += den[b * 16 + k];
    float o = 0.f;
    #pragma unroll
    for (int k = 0; k < 16; ++k) o += P[(size_t)(b * 16 + k) * Dn + t];
    out[(size_t)b * Dn + t] = o / (dtot + EPS_F);
}

extern "C" void kernel_launch(void* const* d_in, const int* in_sizes, int n_in,
                              void* d_out, int out_size, void* d_ws, size_t ws_size,
                              hipStream_t stream) {
    const float* key   = (const float*)d_in[0];
    const float* query = (const float*)d_in[1];
    const int*   mask  = (const int*)d_in[2];
    const float* W     = (const float*)d_in[3];
    const float* bias  = (const float*)d_in[4];
    const float* Wu    = (const float*)d_in[5];
    float* out = (float*)d_out;

    char* ws = (char*)d_ws;
    float*  u   = (float*)(ws);
    ushort* Bhi = (ushort*)(ws + 512);
    ushort* Blo = (ushort*)(ws + 66048);
    float*  Pp  = (float*)(ws + 131584);
    float*  den = (float*)(ws + 2228736);

    hipLaunchKernelGGL(k_u,      dim3(1),    dim3(128), 0, stream, Wu, query, u);
    hipLaunchKernelGGL(k_bprep,  dim3(16),   dim3(256), 0, stream, W, Bhi, Blo);
    hipLaunchKernelGGL(k_scores, dim3(NBLK), dim3(256), 0, stream,
                       key, Bhi, Blo, bias, u, mask, Pp, den);
    hipLaunchKernelGGL(k_final,  dim3(Bn),   dim3(256), 0, stream, Pp, den, out);
}

// Round 4
// 75.165 us; speedup vs baseline: 11.1903x; 1.2308x over previous
//
#include <hip/hip_runtime.h>
#include <hip/hip_bf16.h>
#include <math.h>

#define EPS_F 1e-7f

constexpr int Bn = 128, Sn = 1024, Dn = 256, ATTn = 128, QDn = 128;
constexpr int Mn = Bn * Sn;          // 131072 rows
constexpr int BM = 128;              // rows per block
constexpr int NBLK = Mn / BM;        // 1024 blocks
constexpr int KSTEPS = Dn / 32;      // 8 MFMA k-steps
constexpr int NJ = ATTn / 16;        // 8 column fragments

typedef short short8 __attribute__((ext_vector_type(8)));
typedef float f32x4  __attribute__((ext_vector_type(4)));

// Exact truncation split: f = hi + r exactly (hi = top-16-bit float),
// lo = bf16_rne(r). A_hi*B_hi + A_hi*B_lo + A_lo*B_hi ~ 2^-17 relative.
__device__ inline void split_bf(float f, ushort& hi, ushort& lo) {
    uint fb = __float_as_uint(f);
    hi = (ushort)(fb >> 16);
    float hf = __uint_as_float(fb & 0xffff0000u);
    float lf = f - hf;                       // exact
    __hip_bfloat16 lb = __float2bfloat16(lf);
    __builtin_memcpy(&lo, &lb, 2);
}

__device__ inline float tanh_fast(float x) {
    float cx = fminf(9.0f, fmaxf(-9.0f, x));
    float e = __builtin_amdgcn_exp2f(cx * 2.8853900817779268f);  // e^{2x}
    return (e - 1.0f) * __builtin_amdgcn_rcpf(e + 1.0f);
}

// ---------------- ws layout (bytes) ----------------
// [0,512)              u (128 f32)
// [512,66048)          Bhi (8ks * 8j * 64lane * 8 bf16)
// [66048,131584)       Blo
// [131584,1180160)     P   (1024 blk * 256 d f32)
// [1180160,1184256)    den (1024 f32)

// Merged prep: block 0 computes u = W_u @ query; blocks 1..16 build the
// MFMA-B-fragment-ordered bf16 hi/lo copies of W.
// Fragment (ks,j): lane l holds col = 16j+(l&15), k = 32ks+(l>>4)*8+i.
__global__ __launch_bounds__(256) void k_prep(
    const float* __restrict__ Wu, const float* __restrict__ q,
    float* __restrict__ u,
    const float* __restrict__ W,
    ushort* __restrict__ Bhi, ushort* __restrict__ Blo)
{
    if (blockIdx.x == 0) {
        __shared__ float qs[QDn];
        int t = threadIdx.x;
        if (t < QDn) qs[t] = q[t];
        __syncthreads();
        if (t < ATTn) {
            float acc = 0.f;
            #pragma unroll 8
            for (int j = 0; j < QDn; ++j) acc += Wu[t * QDn + j] * qs[j];
            u[t] = acc;
        }
        return;
    }
    int gid  = (blockIdx.x - 1) * 256 + threadIdx.x;   // 0..4095
    int lane = gid & 63;
    int j    = (gid >> 6) & 7;
    int ks   = gid >> 9;
    int col  = j * 16 + (lane & 15);
    int kb   = ks * 32 + (lane >> 4) * 8;
    #pragma unroll
    for (int i = 0; i < 8; ++i) {
        float f = W[(size_t)(kb + i) * ATTn + col];
        ushort h, l;
        split_bf(f, h, l);
        size_t idx = (size_t)gid * 8 + i;
        Bhi[idx] = h; Blo[idx] = l;
    }
}

// Fused: scores (bf16-split MFMA, K=256, N=128) + partial weighted sums.
// 4 waves; wave w owns rows w*32..w*32+31 as two 16-row fragments.
__global__ __launch_bounds__(256, 3) void k_scores(
    const float*  __restrict__ key,
    const ushort* __restrict__ Bhi, const ushort* __restrict__ Blo,
    const float*  __restrict__ bias, const float* __restrict__ u,
    const int*    __restrict__ mask,
    float* __restrict__ P, float* __restrict__ den)
{
    __shared__ float  es[BM];
    __shared__ float4 part[4][64];
    const int t    = threadIdx.x;
    const int lane = t & 63;
    const int w    = t >> 6;
    const int gb   = blockIdx.x;
    const int row0 = gb * BM;
    const int l15  = lane & 15;
    const int lg   = lane >> 4;

    f32x4 acc[2][NJ];
    #pragma unroll
    for (int rf = 0; rf < 2; ++rf)
        #pragma unroll
        for (int j = 0; j < NJ; ++j) acc[rf][j] = (f32x4){0.f, 0.f, 0.f, 0.f};

    const float* ab0 = key + (size_t)(row0 + w * 32 + l15) * Dn + lg * 8;
    const float* ab1 = ab0 + 16 * Dn;

    // A double-buffer: prefetch next k-step while MFMAing current.
    float4 n00 = *(const float4*)(ab0);
    float4 n01 = *(const float4*)(ab0 + 4);
    float4 n10 = *(const float4*)(ab1);
    float4 n11 = *(const float4*)(ab1 + 4);

    #pragma unroll
    for (int ks = 0; ks < KSTEPS; ++ks) {
        float4 c00 = n00, c01 = n01, c10 = n10, c11 = n11;
        if (ks + 1 < KSTEPS) {
            n00 = *(const float4*)(ab0 + (ks + 1) * 32);
            n01 = *(const float4*)(ab0 + (ks + 1) * 32 + 4);
            n10 = *(const float4*)(ab1 + (ks + 1) * 32);
            n11 = *(const float4*)(ab1 + (ks + 1) * 32 + 4);
        }
        short8 ah[2], al[2];
        {
            float f0[8] = {c00.x, c00.y, c00.z, c00.w, c01.x, c01.y, c01.z, c01.w};
            float f1[8] = {c10.x, c10.y, c10.z, c10.w, c11.x, c11.y, c11.z, c11.w};
            #pragma unroll
            for (int i = 0; i < 8; ++i) {
                ushort h, l;
                split_bf(f0[i], h, l); ah[0][i] = (short)h; al[0][i] = (short)l;
                split_bf(f1[i], h, l); ah[1][i] = (short)h; al[1][i] = (short)l;
            }
        }
        #pragma unroll
        for (int j = 0; j < NJ; ++j) {
            const size_t boff = ((size_t)(ks * NJ + j) * 64 + lane) * 8;
            short8 bh = *(const short8*)(Bhi + boff);
            short8 bl = *(const short8*)(Blo + boff);
            #pragma unroll
            for (int rf = 0; rf < 2; ++rf) {
                acc[rf][j] = __builtin_amdgcn_mfma_f32_16x16x32_bf16(ah[rf], bh, acc[rf][j], 0, 0, 0);
                acc[rf][j] = __builtin_amdgcn_mfma_f32_16x16x32_bf16(ah[rf], bl, acc[rf][j], 0, 0, 0);
                acc[rf][j] = __builtin_amdgcn_mfma_f32_16x16x32_bf16(al[rf], bh, acc[rf][j], 0, 0, 0);
            }
        }
    }

    // Epilogue: s(row) = sum_col tanh(acc+bias)*u; e = exp(s)*mask.
    // C/D layout: col = 16j + l15, row(frag-local) = lg*4 + reg.
    #pragma unroll
    for (int rf = 0; rf < 2; ++rf) {
        float s4[4] = {0.f, 0.f, 0.f, 0.f};
        #pragma unroll
        for (int j = 0; j < NJ; ++j) {
            int col = j * 16 + l15;
            float bv = bias[col], uvv = u[col];
            #pragma unroll
            for (int reg = 0; reg < 4; ++reg)
                s4[reg] += tanh_fast(acc[rf][j][reg] + bv) * uvv;
        }
        #pragma unroll
        for (int reg = 0; reg < 4; ++reg) {
            float s = s4[reg];
            s += __shfl_xor(s, 1);
            s += __shfl_xor(s, 2);
            s += __shfl_xor(s, 4);
            s += __shfl_xor(s, 8);
            if (l15 == 0) {
                int rl = w * 32 + rf * 16 + lg * 4 + reg;
                es[rl] = __builtin_amdgcn_exp2f(s * 1.4426950408889634f)
                         * (float)mask[row0 + rl];
            }
        }
    }
    __syncthreads();

    // block-partial denominator
    if (t < 64) {
        float v = es[t] + es[t + 64];
        #pragma unroll
        for (int m = 1; m < 64; m <<= 1) v += __shfl_xor(v, m);
        if (t == 0) den[gb] = v;
    }

    // phase 2: P[d] = sum_s es[s]*key[row0+s][d]  (tile is L2-hot)
    const int dq = t & 63;          // float4 lane over d
    const int sc = t >> 6;          // s-chunk (32 rows each)
    const float4* key4 = (const float4*)(key + (size_t)row0 * Dn);
    float4 a2 = make_float4(0.f, 0.f, 0.f, 0.f);
    #pragma unroll 4
    for (int s2 = sc * 32; s2 < sc * 32 + 32; ++s2) {
        float wv  = es[s2];
        float4 kv = key4[(size_t)s2 * 64 + dq];
        a2.x += wv * kv.x; a2.y += wv * kv.y;
        a2.z += wv * kv.z; a2.w += wv * kv.w;
    }
    part[sc][dq] = a2;
    __syncthreads();
    if (t < 64) {
        float4 o = part[0][t];
        #pragma unroll
        for (int c = 1; c < 4; ++c) {
            float4 p = part[c][t];
            o.x += p.x; o.y += p.y; o.z += p.z; o.w += p.w;
        }
        *(float4*)(P + (size_t)gb * Dn + t * 4) = o;
    }
}

// combine 8 block-partials per batch, normalize.
__global__ __launch_bounds__(256) void k_final(const float* __restrict__ P,
        const float* __restrict__ den, float* __restrict__ out) {
    int b = blockIdx.x, t = threadIdx.x;
    float dtot = 0.f;
    #pragma unroll
    for (int k = 0; k < 8; ++k) dtot += den[b * 8 + k];
    float o = 0.f;
    #pragma unroll
    for (int k = 0; k < 8; ++k) o += P[(size_t)(b * 8 + k) * Dn + t];
    out[(size_t)b * Dn + t] = o / (dtot + EPS_F);
}

extern "C" void kernel_launch(void* const* d_in, const int* in_sizes, int n_in,
                              void* d_out, int out_size, void* d_ws, size_t ws_size,
                              hipStream_t stream) {
    const float* key   = (const float*)d_in[0];
    const float* query = (const float*)d_in[1];
    const int*   mask  = (const int*)d_in[2];
    const float* W     = (const float*)d_in[3];
    const float* bias  = (const float*)d_in[4];
    const float* Wu    = (const float*)d_in[5];
    float* out = (float*)d_out;

    char* ws = (char*)d_ws;
    float*  u   = (float*)(ws);
    ushort* Bhi = (ushort*)(ws + 512);
    ushort* Blo = (ushort*)(ws + 66048);
    float*  Pp  = (float*)(ws + 131584);
    float*  den = (float*)(ws + 1180160);

    hipLaunchKernelGGL(k_prep,   dim3(17),   dim3(256), 0, stream, Wu, query, u, W, Bhi, Blo);
    hipLaunchKernelGGL(k_scores, dim3(NBLK), dim3(256), 0, stream,
                       key, Bhi, Blo, bias, u, mask, Pp, den);
    hipLaunchKernelGGL(k_final,  dim3(Bn),   dim3(256), 0, stream, Pp, den, out);
}